// Round 18
// baseline (39.237 us; speedup 1.0000x reference)
//
#include <hip/hip_runtime.h>
#include <math.h>

#define HW 256
#define LW 68           // 2 halo + 64 + 2 halo
#define WLH 12          // per-wave tile rows: 8 output + 4 halo
#define NT 4            // horizontal tiles per band

typedef float f32x2 __attribute__((ext_vector_type(2)));

__device__ __forceinline__ int reflect_idx(int i) {
    i = (i < 0) ? -i : i;
    i = (i >= HW) ? (2 * HW - 2 - i) : i;
    return i;
}

__device__ __forceinline__ float4 max4(float4 a, float4 b) {
    float4 r; r.x = fmaxf(a.x, b.x); r.y = fmaxf(a.y, b.y);
    r.z = fmaxf(a.z, b.z); r.w = fmaxf(a.w, b.w); return r;
}
__device__ __forceinline__ float4 max34(float4 a, float4 b, float4 c) {
    float4 r; r.x = fmaxf(fmaxf(a.x, b.x), c.x); r.y = fmaxf(fmaxf(a.y, b.y), c.y);
    r.z = fmaxf(fmaxf(a.z, b.z), c.z); r.w = fmaxf(fmaxf(a.w, b.w), c.w); return r;
}
__device__ __forceinline__ float4 add4(float4 a, float4 b) {
    float4 r; r.x = a.x + b.x; r.y = a.y + b.y;
    r.z = a.z + b.z; r.w = a.w + b.w; return r;
}
__device__ __forceinline__ float4 sub4(float4 a, float4 b) {
    float4 r; r.x = a.x - b.x; r.y = a.y - b.y;
    r.z = a.z - b.z; r.w = a.w - b.w; return r;
}

struct Stage {          // one tile's staged data held in registers (13 VGPRs)
    float m[WLH];
    float h;
};

// The 7 f32x2 pairs a window row ever needs: 4 natural sub-slices of the two
// float4 loads (pair-aligned for VOP3P) + 3 shifted pairs built ONCE per row
// (6 movs, hoisted out of the tap loop). Tap slices for pixel-pair (0,1) are
// j=0..4 -> p0,s1,p1,s3,p2; for (2,3) -> p1,s3,p2,s5,p3.
struct RowP { f32x2 p0, p1, p2, p3, s1, s3, s5; };
__device__ __forceinline__ RowP make_rowp(float4 a, float4 b) {
    RowP r;
    r.p0 = f32x2{a.x, a.y}; r.p1 = f32x2{a.z, a.w};
    r.p2 = f32x2{b.x, b.y}; r.p3 = f32x2{b.z, b.w};
    r.s1 = f32x2{a.y, a.z}; r.s3 = f32x2{a.w, b.x}; r.s5 = f32x2{b.y, b.z};
    return r;
}

// One output row, 4 pixels; tap loop on pre-aligned pairs only.
__device__ __forceinline__ void proc_row(
    float4 A0, float4 B0, float4 A1, float4 B1, float4 A2, float4 B2,
    float4 A3, float4 B3, float4 A4, float4 B4,
    float4 cmA, float4 cmB, float4 csA, float4 csB,
    float bp, float c04b, float inv_bp, float lam,
    float* __restrict__ orow)
{
    const float cs[8] = {csA.x,csA.y,csA.z,csA.w, csB.x,csB.y,csB.z,csB.w};
    const float cm[8] = {cmA.x,cmA.y,cmA.z,cmA.w, cmB.x,cmB.y,cmB.z,cmB.w};

    const float t12 = cs[1] + cs[2];
    const float t34 = cs[3] + cs[4];
    const float t56 = cs[5] + cs[6];
    const float u   = t12 + t34;
    const float w_  = t34 + t56;
    const float S[4] = {cs[0] + u, u + cs[5], cs[2] + w_, w_ + cs[7]};

    const float h12 = fmaxf(cm[1], cm[2]);
    const float h34 = fmaxf(cm[3], cm[4]);
    const float h56 = fmaxf(cm[5], cm[6]);
    const float m[4] = {fmaxf(fmaxf(cm[0], h12), h34),
                        fmaxf(fmaxf(h12, h34), cm[5]),
                        fmaxf(fmaxf(cm[2], h34), h56),
                        fmaxf(fmaxf(h34, h56), cm[7])};

    const f32x2 bp2   = {bp, bp};
    const f32x2 nbm01 = {-(S[0] * c04b), -(S[1] * c04b)};
    const f32x2 nbm23 = {-(S[2] * c04b), -(S[3] * c04b)};
    f32x2 ws01 = {0.0f, 0.0f}, ws23 = {0.0f, 0.0f};
    f32x2 wa01 = {0.0f, 0.0f}, wa23 = {0.0f, 0.0f};

    #define TAP(V01, V23)                                                     \
    do {                                                                      \
        const f32x2 tv01 = __builtin_elementwise_fma(bp2, (V01), nbm01);      \
        const f32x2 tv23 = __builtin_elementwise_fma(bp2, (V23), nbm23);      \
        f32x2 e01, e23;                                                       \
        e01.x = __builtin_amdgcn_exp2f(-fabsf(tv01.x));                       \
        e01.y = __builtin_amdgcn_exp2f(-fabsf(tv01.y));                       \
        e23.x = __builtin_amdgcn_exp2f(-fabsf(tv23.x));                       \
        e23.y = __builtin_amdgcn_exp2f(-fabsf(tv23.y));                       \
        ws01 += e01;                                                          \
        ws23 += e23;                                                          \
        wa01 = __builtin_elementwise_fma(e01, tv01, wa01);                    \
        wa23 = __builtin_elementwise_fma(e23, tv23, wa23);                    \
    } while (0)

    #define ROW_TAPS(A, B)                                                    \
    do {                                                                      \
        const RowP rp = make_rowp((A), (B));                                  \
        TAP(rp.p0, rp.p1);                                                    \
        TAP(rp.s1, rp.s3);                                                    \
        TAP(rp.p1, rp.p2);                                                    \
        TAP(rp.s3, rp.s5);                                                    \
        TAP(rp.p2, rp.p3);                                                    \
    } while (0)

    ROW_TAPS(A0, B0);
    ROW_TAPS(A1, B1);
    ROW_TAPS(A2, B2);
    ROW_TAPS(A3, B3);
    ROW_TAPS(A4, B4);

    #undef ROW_TAPS
    #undef TAP

    const float ws[4] = {ws01.x, ws01.y, ws23.x, ws23.y};
    const float wa[4] = {wa01.x, wa01.y, wa23.x, wa23.y};

    float o[4];
    #pragma unroll
    for (int p = 0; p < 4; ++p) {
        const float mean = S[p] * 0.04f;
        const float med  = fmaf(wa[p] * __builtin_amdgcn_rcpf(ws[p]), inv_bp, mean);
        o[p] = fmaf(lam, med - m[p], m[p]);
    }
    float4 o4; o4.x = o[0]; o4.y = o[1]; o4.z = o[2]; o4.w = o[3];
    *(float4*)orow = o4;
}

__global__ __launch_bounds__(64)
void maxmedian_kernel(const float* __restrict__ x,
                      const float* __restrict__ mix,
                      const float* __restrict__ beta_raw,
                      float* __restrict__ out,
                      int C) {
    // One wave per block; double-buffered 12x68 tile (6.5 KB).
    __shared__ __align__(16) float lds[2][WLH * LW];

    const int lane = threadIdx.x;

    // Each block(=wave) owns one 8-row x 256-col band (4 tiles of 64 cols).
    const int band  = blockIdx.x;              // 0..4095
    const int plane = band >> 5;               // 32 bands per plane
    const int by0   = (band & 31) << 3;        // band's first output row

    const float* __restrict__ xp = x + (size_t)plane * (HW * HW);

    // Row addresses (vertical reflect), constant across the band's tiles.
    int gy[WLH];
    #pragma unroll
    for (int k = 0; k < WLH; ++k) gy[k] = reflect_idx(by0 - 2 + k) * HW;

    // Halo-lane mapping (lanes 0..47): 4 cols x 12 rows.
    const int hj   = lane & 3;
    const int hcol = (hj < 2) ? hj : (64 + hj);        // LDS col 0,1,66,67
    const int hoff = hcol - 2;                         // -2,-1,64,65
    const int gyh  = reflect_idx(by0 - 2 + (lane >> 2)) * HW;

    // ---- Parameters ----
    const int ch = plane % C;
    const float lam  = 1.0f / (1.0f + __expf(-mix[ch]));
    const float beta = 5.0f + 45.0f / (1.0f + __expf(-beta_raw[0]));
    const float bp     = beta * 1.44269504088896f;
    const float inv_bp = 1.0f / bp;
    const float c04b   = 0.04f * bp;

    // Compute-lane mapping: 4 cols x 2 rows per lane.
    const int tx = lane & 15;
    const int r0 = (lane >> 4) * 2;

    auto stage_load = [&](int t, Stage& s) {
        const int c0 = t * 64;
        #pragma unroll
        for (int k = 0; k < WLH; ++k)
            s.m[k] = xp[gy[k] + c0 + lane];
        if (lane < 48)
            s.h = xp[gyh + reflect_idx(c0 + hoff)];
    };
    auto stage_write = [&](int buf, const Stage& s) {
        float* __restrict__ b = lds[buf];
        #pragma unroll
        for (int k = 0; k < WLH; ++k)
            b[k * LW + 2 + lane] = s.m[k];
        if (lane < 48)
            b[(lane >> 2) * LW + hcol] = s.h;
    };
    auto compute = [&](int t, int buf) {
        const float* lbase = &lds[buf][r0 * LW + 4 * tx];

        float4 w0a = *(const float4*)(lbase + 0 * LW);
        float4 w0b = *(const float4*)(lbase + 0 * LW + 4);
        float4 w1a = *(const float4*)(lbase + 1 * LW);
        float4 w1b = *(const float4*)(lbase + 1 * LW + 4);
        float4 w2a = *(const float4*)(lbase + 2 * LW);
        float4 w2b = *(const float4*)(lbase + 2 * LW + 4);
        float4 w3a = *(const float4*)(lbase + 3 * LW);
        float4 w3b = *(const float4*)(lbase + 3 * LW + 4);
        float4 w4a = *(const float4*)(lbase + 4 * LW);
        float4 w4b = *(const float4*)(lbase + 4 * LW + 4);
        float4 w5a = *(const float4*)(lbase + 5 * LW);
        float4 w5b = *(const float4*)(lbase + 5 * LW + 4);

        float4 csA = add4(add4(add4(w0a, w1a), add4(w2a, w3a)), w4a);
        float4 csB = add4(add4(add4(w0b, w1b), add4(w2b, w3b)), w4b);

        const float4 p12a = max4(w1a, w2a), p12b = max4(w1b, w2b);
        const float4 p34a = max4(w3a, w4a), p34b = max4(w3b, w4b);
        const float4 cm0a = max34(w0a, p12a, p34a);
        const float4 cm0b = max34(w0b, p12b, p34b);

        float* __restrict__ orow =
            out + (size_t)plane * (HW * HW) + (size_t)(by0 + r0) * HW + (t * 64 + 4 * tx);

        proc_row(w0a,w0b, w1a,w1b, w2a,w2b, w3a,w3b, w4a,w4b,
                 cm0a, cm0b, csA, csB, bp, c04b, inv_bp, lam, orow);

        csA = add4(csA, sub4(w5a, w0a));
        csB = add4(csB, sub4(w5b, w0b));
        const float4 cm1a = max34(p12a, p34a, w5a);
        const float4 cm1b = max34(p12b, p34b, w5b);

        proc_row(w1a,w1b, w2a,w2b, w3a,w3b, w4a,w4b, w5a,w5b,
                 cm1a, cm1b, csA, csB, bp, c04b, inv_bp, lam, orow + HW);
    };

    // ---- Software pipeline: stage(next) loads in flight under compute(cur).
    Stage s0, s1, s2, s3;
    stage_load(0, s0);
    stage_write(0, s0);
    __builtin_amdgcn_wave_barrier();

    stage_load(1, s1);
    compute(0, 0);
    stage_write(1, s1);
    __builtin_amdgcn_wave_barrier();

    stage_load(2, s2);
    compute(1, 1);
    stage_write(0, s2);
    __builtin_amdgcn_wave_barrier();

    stage_load(3, s3);
    compute(2, 0);
    stage_write(1, s3);
    __builtin_amdgcn_wave_barrier();

    compute(3, 1);
}

extern "C" void kernel_launch(void* const* d_in, const int* in_sizes, int n_in,
                              void* d_out, int out_size, void* d_ws, size_t ws_size,
                              hipStream_t stream) {
    const float* x        = (const float*)d_in[0];
    const float* mix      = (const float*)d_in[1];
    const float* beta_raw = (const float*)d_in[2];
    float* out            = (float*)d_out;

    const int planes = in_sizes[0] / (HW * HW);     // B*C = 128
    const int C      = in_sizes[1];                 // 32
    const int grid = planes * 32;                   // 4096 bands, 1 wave each

    maxmedian_kernel<<<grid, 64, 0, stream>>>(x, mix, beta_raw, out, C);
}

// Round 19
// 36.725 us; speedup vs baseline: 1.0684x; 1.0684x over previous
//
#include <hip/hip_runtime.h>
#include <math.h>

#define HW 256
#define LW 68           // 2 halo + 64 + 2 halo
#define WLH 12          // per-wave tile rows: 8 output + 4 halo
#define NT 4            // horizontal tiles per band

typedef float f32x2 __attribute__((ext_vector_type(2)));

__device__ __forceinline__ int reflect_idx(int i) {
    i = (i < 0) ? -i : i;
    i = (i >= HW) ? (2 * HW - 2 - i) : i;
    return i;
}

__device__ __forceinline__ float4 max4(float4 a, float4 b) {
    float4 r; r.x = fmaxf(a.x, b.x); r.y = fmaxf(a.y, b.y);
    r.z = fmaxf(a.z, b.z); r.w = fmaxf(a.w, b.w); return r;
}
__device__ __forceinline__ float4 max34(float4 a, float4 b, float4 c) {
    float4 r; r.x = fmaxf(fmaxf(a.x, b.x), c.x); r.y = fmaxf(fmaxf(a.y, b.y), c.y);
    r.z = fmaxf(fmaxf(a.z, b.z), c.z); r.w = fmaxf(fmaxf(a.w, b.w), c.w); return r;
}
__device__ __forceinline__ float4 add4(float4 a, float4 b) {
    float4 r; r.x = a.x + b.x; r.y = a.y + b.y;
    r.z = a.z + b.z; r.w = a.w + b.w; return r;
}
__device__ __forceinline__ float4 sub4(float4 a, float4 b) {
    float4 r; r.x = a.x - b.x; r.y = a.y - b.y;
    r.z = a.z - b.z; r.w = a.w - b.w; return r;
}

struct Stage {          // one tile's staged data held in registers (13 VGPRs)
    float m[WLH];
    float h;
};

// One output row, 4 pixels, packed f32x2 tap loop with trans-pipe exp (R13).
__device__ __forceinline__ void proc_row(
    float4 A0, float4 B0, float4 A1, float4 B1, float4 A2, float4 B2,
    float4 A3, float4 B3, float4 A4, float4 B4,
    float4 cmA, float4 cmB, float4 csA, float4 csB,
    float bp, float c04b, float inv_bp, float lam,
    float* __restrict__ orow)
{
    const float cs[8] = {csA.x,csA.y,csA.z,csA.w, csB.x,csB.y,csB.z,csB.w};
    const float cm[8] = {cmA.x,cmA.y,cmA.z,cmA.w, cmB.x,cmB.y,cmB.z,cmB.w};
    const float vv[5][8] = {
        {A0.x,A0.y,A0.z,A0.w, B0.x,B0.y,B0.z,B0.w},
        {A1.x,A1.y,A1.z,A1.w, B1.x,B1.y,B1.z,B1.w},
        {A2.x,A2.y,A2.z,A2.w, B2.x,B2.y,B2.z,B2.w},
        {A3.x,A3.y,A3.z,A3.w, B3.x,B3.y,B3.z,B3.w},
        {A4.x,A4.y,A4.z,A4.w, B4.x,B4.y,B4.z,B4.w}};

    const float t12 = cs[1] + cs[2];
    const float t34 = cs[3] + cs[4];
    const float t56 = cs[5] + cs[6];
    const float u   = t12 + t34;
    const float w_  = t34 + t56;
    const float S[4] = {cs[0] + u, u + cs[5], cs[2] + w_, w_ + cs[7]};

    const float h12 = fmaxf(cm[1], cm[2]);
    const float h34 = fmaxf(cm[3], cm[4]);
    const float h56 = fmaxf(cm[5], cm[6]);
    const float m[4] = {fmaxf(fmaxf(cm[0], h12), h34),
                        fmaxf(fmaxf(h12, h34), cm[5]),
                        fmaxf(fmaxf(cm[2], h34), h56),
                        fmaxf(fmaxf(h34, h56), cm[7])};

    const f32x2 bp2   = {bp, bp};
    const f32x2 nbm01 = {-(S[0] * c04b), -(S[1] * c04b)};
    const f32x2 nbm23 = {-(S[2] * c04b), -(S[3] * c04b)};
    f32x2 ws01 = {0.0f, 0.0f}, ws23 = {0.0f, 0.0f};
    f32x2 wa01 = {0.0f, 0.0f}, wa23 = {0.0f, 0.0f};

    #pragma unroll
    for (int k = 0; k < 5; ++k) {
        #pragma unroll
        for (int j = 0; j < 5; ++j) {
            const f32x2 v01 = {vv[k][j],     vv[k][j + 1]};
            const f32x2 v23 = {vv[k][j + 2], vv[k][j + 3]};
            const f32x2 tv01 = __builtin_elementwise_fma(bp2, v01, nbm01);
            const f32x2 tv23 = __builtin_elementwise_fma(bp2, v23, nbm23);
            f32x2 e01, e23;
            e01.x = __builtin_amdgcn_exp2f(-fabsf(tv01.x));
            e01.y = __builtin_amdgcn_exp2f(-fabsf(tv01.y));
            e23.x = __builtin_amdgcn_exp2f(-fabsf(tv23.x));
            e23.y = __builtin_amdgcn_exp2f(-fabsf(tv23.y));
            ws01 += e01;
            ws23 += e23;
            wa01 = __builtin_elementwise_fma(e01, tv01, wa01);
            wa23 = __builtin_elementwise_fma(e23, tv23, wa23);
        }
    }

    const float ws[4] = {ws01.x, ws01.y, ws23.x, ws23.y};
    const float wa[4] = {wa01.x, wa01.y, wa23.x, wa23.y};

    float o[4];
    #pragma unroll
    for (int p = 0; p < 4; ++p) {
        const float mean = S[p] * 0.04f;
        const float med  = fmaf(wa[p] * __builtin_amdgcn_rcpf(ws[p]), inv_bp, mean);
        o[p] = fmaf(lam, med - m[p], m[p]);
    }
    float4 o4; o4.x = o[0]; o4.y = o[1]; o4.z = o[2]; o4.w = o[3];
    *(float4*)orow = o4;
}

__global__ __launch_bounds__(64)
void maxmedian_kernel(const float* __restrict__ x,
                      const float* __restrict__ mix,
                      const float* __restrict__ beta_raw,
                      float* __restrict__ out,
                      int C) {
    // One wave per block; double-buffered 12x68 tile (6.5 KB).
    __shared__ __align__(16) float lds[2][WLH * LW];

    const int lane = threadIdx.x;

    // Bijective XCD swizzle (4096 % 8 == 0): contiguous 512-band chunks per
    // XCD so adjacent bands (which share 4 halo rows) hit the same L2.
    const int nwg  = gridDim.x;                // 4096
    const int cpx  = nwg >> 3;                 // 512 bands per XCD
    const int band = (blockIdx.x % 8) * cpx + (blockIdx.x >> 3);

    const int plane = band >> 5;               // 32 bands per plane
    const int by0   = (band & 31) << 3;        // band's first output row

    const float* __restrict__ xp = x + (size_t)plane * (HW * HW);

    // Row addresses (vertical reflect), constant across the band's tiles.
    int gy[WLH];
    #pragma unroll
    for (int k = 0; k < WLH; ++k) gy[k] = reflect_idx(by0 - 2 + k) * HW;

    // Halo-lane mapping (lanes 0..47): 4 cols x 12 rows.
    const int hj   = lane & 3;
    const int hcol = (hj < 2) ? hj : (64 + hj);        // LDS col 0,1,66,67
    const int hoff = hcol - 2;                         // -2,-1,64,65
    const int gyh  = reflect_idx(by0 - 2 + (lane >> 2)) * HW;

    // ---- Parameters ----
    const int ch = plane % C;
    const float lam  = 1.0f / (1.0f + __expf(-mix[ch]));
    const float beta = 5.0f + 45.0f / (1.0f + __expf(-beta_raw[0]));
    const float bp     = beta * 1.44269504088896f;
    const float inv_bp = 1.0f / bp;
    const float c04b   = 0.04f * bp;

    // Compute-lane mapping: 4 cols x 2 rows per lane.
    const int tx = lane & 15;
    const int r0 = (lane >> 4) * 2;

    auto stage_load = [&](int t, Stage& s) {
        const int c0 = t * 64;
        #pragma unroll
        for (int k = 0; k < WLH; ++k)
            s.m[k] = xp[gy[k] + c0 + lane];
        if (lane < 48)
            s.h = xp[gyh + reflect_idx(c0 + hoff)];
    };
    auto stage_write = [&](int buf, const Stage& s) {
        float* __restrict__ b = lds[buf];
        #pragma unroll
        for (int k = 0; k < WLH; ++k)
            b[k * LW + 2 + lane] = s.m[k];
        if (lane < 48)
            b[(lane >> 2) * LW + hcol] = s.h;
    };
    auto compute = [&](int t, int buf) {
        const float* lbase = &lds[buf][r0 * LW + 4 * tx];

        float4 w0a = *(const float4*)(lbase + 0 * LW);
        float4 w0b = *(const float4*)(lbase + 0 * LW + 4);
        float4 w1a = *(const float4*)(lbase + 1 * LW);
        float4 w1b = *(const float4*)(lbase + 1 * LW + 4);
        float4 w2a = *(const float4*)(lbase + 2 * LW);
        float4 w2b = *(const float4*)(lbase + 2 * LW + 4);
        float4 w3a = *(const float4*)(lbase + 3 * LW);
        float4 w3b = *(const float4*)(lbase + 3 * LW + 4);
        float4 w4a = *(const float4*)(lbase + 4 * LW);
        float4 w4b = *(const float4*)(lbase + 4 * LW + 4);
        float4 w5a = *(const float4*)(lbase + 5 * LW);
        float4 w5b = *(const float4*)(lbase + 5 * LW + 4);

        float4 csA = add4(add4(add4(w0a, w1a), add4(w2a, w3a)), w4a);
        float4 csB = add4(add4(add4(w0b, w1b), add4(w2b, w3b)), w4b);

        const float4 p12a = max4(w1a, w2a), p12b = max4(w1b, w2b);
        const float4 p34a = max4(w3a, w4a), p34b = max4(w3b, w4b);
        const float4 cm0a = max34(w0a, p12a, p34a);
        const float4 cm0b = max34(w0b, p12b, p34b);

        float* __restrict__ orow =
            out + (size_t)plane * (HW * HW) + (size_t)(by0 + r0) * HW + (t * 64 + 4 * tx);

        proc_row(w0a,w0b, w1a,w1b, w2a,w2b, w3a,w3b, w4a,w4b,
                 cm0a, cm0b, csA, csB, bp, c04b, inv_bp, lam, orow);

        csA = add4(csA, sub4(w5a, w0a));
        csB = add4(csB, sub4(w5b, w0b));
        const float4 cm1a = max34(p12a, p34a, w5a);
        const float4 cm1b = max34(p12b, p34b, w5b);

        proc_row(w1a,w1b, w2a,w2b, w3a,w3b, w4a,w4b, w5a,w5b,
                 cm1a, cm1b, csA, csB, bp, c04b, inv_bp, lam, orow + HW);
    };

    // ---- Software pipeline: stage(next) loads in flight under compute(cur).
    Stage s0, s1, s2, s3;
    stage_load(0, s0);
    stage_write(0, s0);
    __builtin_amdgcn_wave_barrier();

    stage_load(1, s1);
    compute(0, 0);
    stage_write(1, s1);
    __builtin_amdgcn_wave_barrier();

    stage_load(2, s2);
    compute(1, 1);
    stage_write(0, s2);
    __builtin_amdgcn_wave_barrier();

    stage_load(3, s3);
    compute(2, 0);
    stage_write(1, s3);
    __builtin_amdgcn_wave_barrier();

    compute(3, 1);
}

extern "C" void kernel_launch(void* const* d_in, const int* in_sizes, int n_in,
                              void* d_out, int out_size, void* d_ws, size_t ws_size,
                              hipStream_t stream) {
    const float* x        = (const float*)d_in[0];
    const float* mix      = (const float*)d_in[1];
    const float* beta_raw = (const float*)d_in[2];
    float* out            = (float*)d_out;

    const int planes = in_sizes[0] / (HW * HW);     // B*C = 128
    const int C      = in_sizes[1];                 // 32
    const int grid = planes * 32;                   // 4096 bands, 1 wave each

    maxmedian_kernel<<<grid, 64, 0, stream>>>(x, mix, beta_raw, out, C);
}